// Round 10
// baseline (363.409 us; speedup 1.0000x reference)
//
#include <hip/hip_runtime.h>
#include <hip/hip_bf16.h>

typedef __attribute__((ext_vector_type(4))) float f32x4;
typedef __attribute__((ext_vector_type(16))) float f32x16;
typedef __attribute__((ext_vector_type(4))) float fl4;
typedef __attribute__((ext_vector_type(8))) short s16x8;
typedef __attribute__((ext_vector_type(4))) short s16x4;

#define SCALING_C 0.1889822365046136f
// 50*tanh(y/50) = y*(1 + y2*(P1 + y2*P2))
#define POLY_P1 (-1.3333333333e-4f)
#define POLY_P2 (2.1333333333e-8f)
#define QKV_STRIDE 6144

__device__ __forceinline__ short f2bf(float f) {
  union { float f; unsigned u; } v; v.f = f;
  unsigned r = v.u + 0x7fffu + ((v.u >> 16) & 1u);
  return (short)(r >> 16);
}
__device__ __forceinline__ float bf2f(short s) {
  union { unsigned u; float f; } v; v.u = ((unsigned)(unsigned short)s) << 16;
  return v.f;
}
__device__ __forceinline__ unsigned pkbf(float a, float b) {
  return (unsigned)(unsigned short)f2bf(a) | ((unsigned)(unsigned short)f2bf(b) << 16);
}

#define GLOAD_LDS16(g, l)                                                          \
  __builtin_amdgcn_global_load_lds(                                                \
      (const __attribute__((address_space(1))) void*)(g),                          \
      (__attribute__((address_space(3))) void*)(l), 16, 0, 0)

// ---------------- transpose + fp32->bf16 convert: WT[n][k] = bf16(W[k][n]) -----
__global__ __launch_bounds__(256)
void convT_kernel(const float* __restrict__ W, short* __restrict__ WT, int K, int N) {
  __shared__ float T[64][65];
  const int tx = threadIdx.x, ty = threadIdx.y;   // (64,4)
  const int k0 = blockIdx.x * 64, n0 = blockIdx.y * 64;
#pragma unroll
  for (int i = 0; i < 16; ++i) {
    int r = ty + i * 4;
    T[r][tx] = W[(size_t)(k0 + r) * N + n0 + tx];
  }
  __syncthreads();
#pragma unroll
  for (int i = 0; i < 16; ++i) {
    int r = ty + i * 4;
    WT[(size_t)(n0 + r) * K + k0 + tx] = f2bf(T[tx][r]);
  }
}

// ---------------- fp32 -> bf16 elementwise (hidden states) ----------------
__global__ __launch_bounds__(256)
void conv16_kernel(const float* __restrict__ X, short* __restrict__ Y, int n4) {
  int i = blockIdx.x * 256 + threadIdx.x;
  if (i < n4) {
    fl4 v = *(const fl4*)&X[(size_t)i * 4];
    s16x4 o;
    o[0] = f2bf(v[0]); o[1] = f2bf(v[1]); o[2] = f2bf(v[2]); o[3] = f2bf(v[3]);
    *(s16x4*)&Y[(size_t)i * 4] = o;
  }
}

// ---------------- GEMM: C = A @ Bt^T ; A MxK bf16 rows, Bt NxK bf16 rows -------
template<int OUT_BF16>
__global__ __launch_bounds__(256)
void gemm_bb(const short* __restrict__ A, const short* __restrict__ Bt,
             void* __restrict__ Cv, int N, int K) {
  __shared__ short As[8192];   // 128 rows x 64 shorts
  __shared__ short Bs[8192];
  const int tid = threadIdx.x;
  const int bm = blockIdx.y, bn = blockIdx.x;
  const int wid = tid >> 6, lane = tid & 63;
  const int wr = (wid >> 1) * 64, wc = (wid & 1) * 64;
  const int ar = lane & 15, g = lane >> 4;

  const f32x4 fz = {0.f, 0.f, 0.f, 0.f};
  f32x4 acc[4][4];
#pragma unroll
  for (int m = 0; m < 4; ++m)
#pragma unroll
    for (int n = 0; n < 4; ++n) acc[m][n] = fz;

  const short* Abase = A + (size_t)(bm * 128) * K;
  const short* Bbase = Bt + (size_t)(bn * 128) * K;
  const int u0 = wid * 256 + lane;

  for (int k0 = 0; k0 < K; k0 += 64) {
#pragma unroll
    for (int i = 0; i < 4; ++i) {
      int u = u0 + i * 64;
      int r = u >> 3;
      int cs = (u & 7) ^ (r & 7);
      size_t goff = (size_t)r * K + k0 + cs * 8;
      GLOAD_LDS16(Abase + goff, &As[(wid * 256 + i * 64) * 8]);
      GLOAD_LDS16(Bbase + goff, &Bs[(wid * 256 + i * 64) * 8]);
    }
    __syncthreads();
#pragma unroll
    for (int ks = 0; ks < 2; ++ks) {
      s16x8 af[4], bfr[4];
#pragma unroll
      for (int m = 0; m < 4; ++m) {
        int r = wr + m * 16 + ar;
        af[m] = *(const s16x8*)&As[r * 64 + (((ks * 4 + g) ^ (r & 7)) * 8)];
      }
#pragma unroll
      for (int n = 0; n < 4; ++n) {
        int r = wc + n * 16 + ar;
        bfr[n] = *(const s16x8*)&Bs[r * 64 + (((ks * 4 + g) ^ (r & 7)) * 8)];
      }
#pragma unroll
      for (int m = 0; m < 4; ++m)
#pragma unroll
        for (int n = 0; n < 4; ++n)
          acc[m][n] = __builtin_amdgcn_mfma_f32_16x16x32_bf16(af[m], bfr[n], acc[m][n], 0, 0, 0);
    }
    __syncthreads();
  }
  const int rr = (lane >> 4) * 4;
#pragma unroll
  for (int m = 0; m < 4; ++m)
#pragma unroll
    for (int n = 0; n < 4; ++n)
#pragma unroll
      for (int j = 0; j < 4; ++j) {
        int row = bm * 128 + wr + m * 16 + rr + j;
        int col = bn * 128 + wc + n * 16 + ar;
        if (OUT_BF16)
          ((short*)Cv)[(size_t)row * N + col] = f2bf(acc[m][n][j]);
        else
          ((float*)Cv)[(size_t)row * N + col] = acc[m][n][j];
      }
}

// ------- fused RMSNorm + RoPE on a column-slice of the fused QKV matrix --------
__global__ __launch_bounds__(256)
void normrope_kernel(short* __restrict__ X, const float* __restrict__ cosb,
                     const float* __restrict__ sinb, const float* __restrict__ w,
                     int hbits, int off) {
  const int wid = threadIdx.x >> 6, lane = threadIdx.x & 63;
  const int r = blockIdx.x * 4 + wid;
  const int s = r >> hbits, h = r & ((1 << hbits) - 1);
  const size_t base = (size_t)s * QKV_STRIDE + off + h * 128;
  float x1 = bf2f(X[base + lane]);
  float x2 = bf2f(X[base + 64 + lane]);
  float ss = x1 * x1 + x2 * x2;
#pragma unroll
  for (int m = 1; m < 64; m <<= 1) ss += __shfl_xor(ss, m);
  float inv = rsqrtf(ss * (1.0f / 128.0f) + 1e-6f);
  float n1 = x1 * inv * (1.0f + w[lane]);
  float n2 = x2 * inv * (1.0f + w[lane + 64]);
  float c1 = cosb[s * 128 + lane], sn1 = sinb[s * 128 + lane];
  float c2 = cosb[s * 128 + 64 + lane], sn2 = sinb[s * 128 + 64 + lane];
  X[base + lane] = f2bf(n1 * c1 - n2 * sn1);
  X[base + 64 + lane] = f2bf(n2 * c2 + n1 * sn2);
}

// ------------- flash attention v6: 2-wave 64-q blocks, KBLK=32, 6 blocks/CU ----
// Block (bx,h): chunk c = 31-bx (LPT), 64 q rows, 2 waves x 32 q. Tiles of 32 kv,
// NT = 2c+2. Grid (32,32)=1024 blocks, 24KB LDS -> 6 blocks/CU (12 waves, 3/SIMD).
// 32x32 swapped-operand QK^T; in-register softmax (fixed max, poly softcap);
// P->A-frag via pack+shfl_xor(32); K dbuf global_load_lds; V reg-staged (16 VGPR).
__global__ __launch_bounds__(128, 3)
void attn_kernel(const short* __restrict__ C, short* __restrict__ O) {
  __shared__ short Ks[2][4096];   // [kv 32][d 128], 16B-chunk XOR-swizzled (r&7)
  __shared__ short Vt[4096];      // [d 128][kv 32], chunk ^ ((d>>2)&3)
  const int tid = threadIdx.x;
  const int h = blockIdx.y, hk = h >> 2;
  const int wid = tid >> 6, lane = tid & 63;
  const int q32 = lane & 31, hi = lane >> 5;
  const int c = 31 - (int)blockIdx.x;          // LPT: big chunks dispatch first
  const int qw0 = c * 64 + wid * 32;           // wave's 32 q-rows
  const int NT = 2 * c + 2;                    // 32-kv tiles

  const short* Kb = C + 4096 + hk * 128;
  const short* Vb = C + 5120 + hk * 128;
  const int vkv = (tid & 15) * 2;              // V stage: kv pair (0..30)
  const int vdb = tid >> 4;                    // V stage: d block of 16 (0..7)

  s16x8 qf[8], vld[4];
  f32x16 oacc[4];
  float l_part = 0.f;

  const short* Qrow = C + (size_t)(qw0 + q32) * QKV_STRIDE + h * 128 + hi * 8;
#pragma unroll
  for (int t = 0; t < 8; ++t) qf[t] = *(const s16x8*)(Qrow + t * 16);
#pragma unroll
  for (int db = 0; db < 4; ++db)
#pragma unroll
    for (int r = 0; r < 16; ++r) oacc[db][r] = 0.f;

  auto issueK = [&](int b, int kb) {
#pragma unroll
    for (int i = 0; i < 4; ++i) {
      int u = tid + i * 128;
      int r = u >> 4, cc = u & 15;
      int cs = cc ^ (r & 7);
      GLOAD_LDS16(Kb + (size_t)(kb * 32 + r) * QKV_STRIDE + cs * 8, &Ks[b][u * 8]);
    }
  };
  auto loadV = [&](int kb) {
    const short* src = Vb + (size_t)(kb * 32 + vkv) * QKV_STRIDE + vdb * 16;
    vld[0] = *(const s16x8*)(src);
    vld[1] = *(const s16x8*)(src + 8);
    vld[2] = *(const s16x8*)(src + QKV_STRIDE);
    vld[3] = *(const s16x8*)(src + QKV_STRIDE + 8);
  };
  auto writeVt = [&]() {
#pragma unroll
    for (int c2 = 0; c2 < 2; ++c2)
#pragma unroll
      for (int j = 0; j < 8; ++j) {
        int d = vdb * 16 + c2 * 8 + j;
        int chunk = (vkv >> 3) ^ ((d >> 2) & 3);
        int addr = d * 32 + chunk * 8 + (vkv & 7);
        unsigned lo = (unsigned short)vld[c2][j];
        unsigned hh = (unsigned short)vld[2 + c2][j];
        *(unsigned*)&Vt[addr] = lo | (hh << 16);
      }
  };

  issueK(0, 0);
  loadV(0);
  asm volatile("s_waitcnt vmcnt(0)" ::: "memory");
  writeVt();
  __syncthreads();

  int buf = 0;
  for (int kb = 0; kb < NT; ++kb) {
    if (kb + 1 < NT) { issueK(buf ^ 1, kb + 1); loadV(kb + 1); }

    const bool skipw = (kb * 32 > qw0 + 31);   // wave fully masked
    if (!skipw) {
      // ---- S^T = K Q^T : sacc[r] = S[k=kb*32+crow(r,hi)][q=qw0+q32] ----
      f32x16 sacc;
#pragma unroll
      for (int r = 0; r < 16; ++r) sacc[r] = 0.f;
      __builtin_amdgcn_s_setprio(1);
#pragma unroll
      for (int t = 0; t < 8; ++t) {
        s16x8 kf = *(const s16x8*)&Ks[buf][q32 * 128 + (((2 * t + hi) ^ (q32 & 7)) * 8)];
        sacc = __builtin_amdgcn_mfma_f32_32x32x16_bf16(kf, qf[t], sacc, 0, 0, 0);
      }
      __builtin_amdgcn_s_setprio(0);

      // ---- softcap + exp (fixed max 0), causal mask ----
      const bool anymask = (kb * 32 + 31 > qw0);
#pragma unroll
      for (int r = 0; r < 16; ++r) {
        float y = sacc[r] * SCALING_C;
        float y2 = y * y;
        float sc = y * fmaf(y2, fmaf(y2, POLY_P2, POLY_P1), 1.0f);
        float p = __expf(sc);
        if (anymask) {
          int kk = kb * 32 + (r & 3) + 8 * (r >> 2) + 4 * hi;
          if (kk > qw0 + q32) p = 0.f;
        }
        l_part += p;
        sacc[r] = p;
      }

      // ---- P -> A-frags (pack + shfl_xor 32) ; O += P V ----
#pragma unroll
      for (int ks = 0; ks < 2; ++ks) {
        const int r0 = ks * 8;
        unsigned a0 = pkbf(sacc[r0 + 0], sacc[r0 + 1]);
        unsigned a1 = pkbf(sacc[r0 + 2], sacc[r0 + 3]);
        unsigned b0 = pkbf(sacc[r0 + 4], sacc[r0 + 5]);
        unsigned b1 = pkbf(sacc[r0 + 6], sacc[r0 + 7]);
        unsigned xa0 = (unsigned)__shfl_xor((int)a0, 32);
        unsigned xa1 = (unsigned)__shfl_xor((int)a1, 32);
        unsigned xb0 = (unsigned)__shfl_xor((int)b0, 32);
        unsigned xb1 = (unsigned)__shfl_xor((int)b1, 32);
        union { s16x8 v; unsigned w[4]; } pw;
        pw.w[0] = hi ? xb0 : a0;
        pw.w[1] = hi ? xb1 : a1;
        pw.w[2] = hi ? b0 : xa0;
        pw.w[3] = hi ? b1 : xa1;
        __builtin_amdgcn_s_setprio(1);
#pragma unroll
        for (int db = 0; db < 4; ++db) {
          int d = db * 32 + q32;
          s16x8 vf = *(const s16x8*)&Vt[d * 32 + (((2 * ks + hi) ^ ((d >> 2) & 3)) * 8)];
          oacc[db] = __builtin_amdgcn_mfma_f32_32x32x16_bf16(pw.v, vf, oacc[db], 0, 0, 0);
        }
        __builtin_amdgcn_s_setprio(0);
      }
    }

    __syncthreads();                 // everyone done reading Ks[buf]/Vt
    if (kb + 1 < NT) {
      asm volatile("s_waitcnt vmcnt(0)" ::: "memory");
      writeVt();
    }
    __syncthreads();                 // next K/V published
    buf ^= 1;
  }

  // ---- epilogue: l gather, divide, store ----
  float lt = l_part + __shfl_xor(l_part, 32);
  float rl[16];
#pragma unroll
  for (int r = 0; r < 16; ++r)
    rl[r] = 1.0f / __shfl(lt, (r & 3) + 8 * (r >> 2) + 4 * hi);
#pragma unroll
  for (int db = 0; db < 4; ++db)
#pragma unroll
    for (int r = 0; r < 16; ++r) {
      int q = qw0 + (r & 3) + 8 * (r >> 2) + 4 * hi;
      int d = db * 32 + q32;
      O[(size_t)q * 4096 + h * 128 + d] = f2bf(oacc[db][r] * rl[r]);
    }
}

extern "C" void kernel_launch(void* const* d_in, const int* in_sizes, int n_in,
                              void* d_out, int out_size, void* d_ws, size_t ws_size,
                              hipStream_t stream) {
  const float* hs   = (const float*)d_in[0];
  const float* cosb = (const float*)d_in[1];
  const float* sinb = (const float*)d_in[2];
  // d_in[3]: causal mask, applied analytically
  const float* Wq = (const float*)d_in[4];
  const float* Wk = (const float*)d_in[5];
  const float* Wv = (const float*)d_in[6];
  const float* Wo = (const float*)d_in[7];
  const float* qw = (const float*)d_in[8];
  const float* kw = (const float*)d_in[9];
  float* out = (float*)d_out;

  char* ws = (char*)d_ws;
  short* hsb = (short*)ws;                        // [0, 10.49M)  2048x2560
  short* WT  = (short*)(ws + 10485760);           // [10.49, 41.94M) 6144x2560 fused
  short* WkT = WT + (size_t)4096 * 2560;
  short* WvT = WT + (size_t)5120 * 2560;
  short* Cq  = (short*)(ws + 41943040);           // [41.94, 67.11M) 2048x6144 QKV
  short* ao  = (short*)ws;                        // alias hsb+WT-head (dead)
  short* WoT = (short*)(ws + 20971520);           // alias WT-tail (dead after QKV gemm)

  dim3 blk(256), cblk(64, 4);
  convT_kernel<<<dim3(40, 64), cblk, 0, stream>>>(Wq, WT, 2560, 4096);
  convT_kernel<<<dim3(40, 16), cblk, 0, stream>>>(Wk, WkT, 2560, 1024);
  convT_kernel<<<dim3(40, 16), cblk, 0, stream>>>(Wv, WvT, 2560, 1024);
  conv16_kernel<<<5120, blk, 0, stream>>>(hs, hsb, 1310720);
  gemm_bb<1><<<dim3(48, 16), blk, 0, stream>>>(hsb, WT, Cq, 6144, 2560);
  normrope_kernel<<<16384, blk, 0, stream>>>(Cq, cosb, sinb, qw, 5, 0);
  normrope_kernel<<<4096,  blk, 0, stream>>>(Cq, cosb, sinb, kw, 3, 4096);
  convT_kernel<<<dim3(64, 40), cblk, 0, stream>>>(Wo, WoT, 4096, 2560);
  attn_kernel<<<dim3(32, 32), dim3(128), 0, stream>>>(Cq, ao);
  gemm_bb<0><<<dim3(20, 16), blk, 0, stream>>>(ao, WoT, out, 2560, 4096);
}

// Round 12
// 285.643 us; speedup vs baseline: 1.2722x; 1.2722x over previous
//
#include <hip/hip_runtime.h>
#include <hip/hip_bf16.h>

typedef __attribute__((ext_vector_type(4))) float f32x4;
typedef __attribute__((ext_vector_type(16))) float f32x16;
typedef __attribute__((ext_vector_type(4))) float fl4;
typedef __attribute__((ext_vector_type(8))) short s16x8;
typedef __attribute__((ext_vector_type(4))) short s16x4;

#define SCALING_C 0.1889822365046136f
// 50*tanh(y/50) = y*(1 + y2*(P1 + y2*P2))
#define POLY_P1 (-1.3333333333e-4f)
#define POLY_P2 (2.1333333333e-8f)
#define QKV_STRIDE 6144

__device__ __forceinline__ short f2bf(float f) {
  union { float f; unsigned u; } v; v.f = f;
  unsigned r = v.u + 0x7fffu + ((v.u >> 16) & 1u);
  return (short)(r >> 16);
}
__device__ __forceinline__ float bf2f(short s) {
  union { unsigned u; float f; } v; v.u = ((unsigned)(unsigned short)s) << 16;
  return v.f;
}
__device__ __forceinline__ unsigned pkbf(float a, float b) {
  return (unsigned)(unsigned short)f2bf(a) | ((unsigned)(unsigned short)f2bf(b) << 16);
}

#define GLOAD_LDS16(g, l)                                                          \
  __builtin_amdgcn_global_load_lds(                                                \
      (const __attribute__((address_space(1))) void*)(g),                          \
      (__attribute__((address_space(3))) void*)(l), 16, 0, 0)

// ---------------- transpose + fp32->bf16 convert: WT[n][k] = bf16(W[k][n]) -----
__global__ __launch_bounds__(256)
void convT_kernel(const float* __restrict__ W, short* __restrict__ WT, int K, int N) {
  __shared__ float T[64][65];
  const int tx = threadIdx.x, ty = threadIdx.y;   // (64,4)
  const int k0 = blockIdx.x * 64, n0 = blockIdx.y * 64;
#pragma unroll
  for (int i = 0; i < 16; ++i) {
    int r = ty + i * 4;
    T[r][tx] = W[(size_t)(k0 + r) * N + n0 + tx];
  }
  __syncthreads();
#pragma unroll
  for (int i = 0; i < 16; ++i) {
    int r = ty + i * 4;
    WT[(size_t)(n0 + r) * K + k0 + tx] = f2bf(T[tx][r]);
  }
}

// ---------------- bf16 transpose of the V slice: Vtg[g][d][kv] -----------------
__global__ __launch_bounds__(256)
void transV_kernel(const short* __restrict__ Vsrc, short* __restrict__ Vtg) {
  __shared__ short T[64][72];
  const int tx = threadIdx.x, ty = threadIdx.y;   // (64,4)
  const int kv0 = blockIdx.x * 64, d0 = blockIdx.y * 64, g = blockIdx.z;
  const short* src = Vsrc + (size_t)kv0 * QKV_STRIDE + g * 128 + d0;
#pragma unroll
  for (int i = 0; i < 16; ++i) {
    int r = ty + i * 4;
    T[r][tx] = src[(size_t)r * QKV_STRIDE + tx];
  }
  __syncthreads();
  short* dst = Vtg + (size_t)g * 128 * 2048 + (size_t)d0 * 2048 + kv0;
#pragma unroll
  for (int i = 0; i < 16; ++i) {
    int r = ty + i * 4;
    dst[(size_t)r * 2048 + tx] = T[tx][r];
  }
}

// ---------------- fp32 -> bf16 elementwise (hidden states) ----------------
__global__ __launch_bounds__(256)
void conv16_kernel(const float* __restrict__ X, short* __restrict__ Y, int n4) {
  int i = blockIdx.x * 256 + threadIdx.x;
  if (i < n4) {
    fl4 v = *(const fl4*)&X[(size_t)i * 4];
    s16x4 o;
    o[0] = f2bf(v[0]); o[1] = f2bf(v[1]); o[2] = f2bf(v[2]); o[3] = f2bf(v[3]);
    *(s16x4*)&Y[(size_t)i * 4] = o;
  }
}

// ---------------- GEMM: C = A @ Bt^T ; A MxK bf16 rows, Bt NxK bf16 rows -------
template<int OUT_BF16>
__global__ __launch_bounds__(256)
void gemm_bb(const short* __restrict__ A, const short* __restrict__ Bt,
             void* __restrict__ Cv, int N, int K) {
  __shared__ short As[8192];   // 128 rows x 64 shorts
  __shared__ short Bs[8192];
  const int tid = threadIdx.x;
  const int bm = blockIdx.y, bn = blockIdx.x;
  const int wid = tid >> 6, lane = tid & 63;
  const int wr = (wid >> 1) * 64, wc = (wid & 1) * 64;
  const int ar = lane & 15, g = lane >> 4;

  const f32x4 fz = {0.f, 0.f, 0.f, 0.f};
  f32x4 acc[4][4];
#pragma unroll
  for (int m = 0; m < 4; ++m)
#pragma unroll
    for (int n = 0; n < 4; ++n) acc[m][n] = fz;

  const short* Abase = A + (size_t)(bm * 128) * K;
  const short* Bbase = Bt + (size_t)(bn * 128) * K;
  const int u0 = wid * 256 + lane;

  for (int k0 = 0; k0 < K; k0 += 64) {
#pragma unroll
    for (int i = 0; i < 4; ++i) {
      int u = u0 + i * 64;
      int r = u >> 3;
      int cs = (u & 7) ^ (r & 7);
      size_t goff = (size_t)r * K + k0 + cs * 8;
      GLOAD_LDS16(Abase + goff, &As[(wid * 256 + i * 64) * 8]);
      GLOAD_LDS16(Bbase + goff, &Bs[(wid * 256 + i * 64) * 8]);
    }
    __syncthreads();
#pragma unroll
    for (int ks = 0; ks < 2; ++ks) {
      s16x8 af[4], bfr[4];
#pragma unroll
      for (int m = 0; m < 4; ++m) {
        int r = wr + m * 16 + ar;
        af[m] = *(const s16x8*)&As[r * 64 + (((ks * 4 + g) ^ (r & 7)) * 8)];
      }
#pragma unroll
      for (int n = 0; n < 4; ++n) {
        int r = wc + n * 16 + ar;
        bfr[n] = *(const s16x8*)&Bs[r * 64 + (((ks * 4 + g) ^ (r & 7)) * 8)];
      }
#pragma unroll
      for (int m = 0; m < 4; ++m)
#pragma unroll
        for (int n = 0; n < 4; ++n)
          acc[m][n] = __builtin_amdgcn_mfma_f32_16x16x32_bf16(af[m], bfr[n], acc[m][n], 0, 0, 0);
    }
    __syncthreads();
  }
  const int rr = (lane >> 4) * 4;
#pragma unroll
  for (int m = 0; m < 4; ++m)
#pragma unroll
    for (int n = 0; n < 4; ++n)
#pragma unroll
      for (int j = 0; j < 4; ++j) {
        int row = bm * 128 + wr + m * 16 + rr + j;
        int col = bn * 128 + wc + n * 16 + ar;
        if (OUT_BF16)
          ((short*)Cv)[(size_t)row * N + col] = f2bf(acc[m][n][j]);
        else
          ((float*)Cv)[(size_t)row * N + col] = acc[m][n][j];
      }
}

// ------- fused RMSNorm + RoPE on a column-slice of the fused QKV matrix --------
__global__ __launch_bounds__(256)
void normrope_kernel(short* __restrict__ X, const float* __restrict__ cosb,
                     const float* __restrict__ sinb, const float* __restrict__ w,
                     int hbits, int off) {
  const int wid = threadIdx.x >> 6, lane = threadIdx.x & 63;
  const int r = blockIdx.x * 4 + wid;
  const int s = r >> hbits, h = r & ((1 << hbits) - 1);
  const size_t base = (size_t)s * QKV_STRIDE + off + h * 128;
  float x1 = bf2f(X[base + lane]);
  float x2 = bf2f(X[base + 64 + lane]);
  float ss = x1 * x1 + x2 * x2;
#pragma unroll
  for (int m = 1; m < 64; m <<= 1) ss += __shfl_xor(ss, m);
  float inv = rsqrtf(ss * (1.0f / 128.0f) + 1e-6f);
  float n1 = x1 * inv * (1.0f + w[lane]);
  float n2 = x2 * inv * (1.0f + w[lane + 64]);
  float c1 = cosb[s * 128 + lane], sn1 = sinb[s * 128 + lane];
  float c2 = cosb[s * 128 + 64 + lane], sn2 = sinb[s * 128 + 64 + lane];
  X[base + lane] = f2bf(n1 * c1 - n2 * sn1);
  X[base + 64 + lane] = f2bf(n2 * c2 + n1 * sn2);
}

// ------------- flash attention v7b: all-gload_lds dbuf, XCD-pinned -------------
// 512 blocks x 4 waves; bid -> (g=bid&7 kv-head==XCD, h=g*4+(i&3), chunk c=15-(i>>2)
// LPT). Per-XCD L2 set: K+V(1MB)+Q(2MB) < 4MB -> steady-state tile loads are L2
// hits. K and pre-transposed V both stream via global_load_lds double-buffers;
// ONE barrier per tile (own-wave vmcnt(0) + s_barrier orders everything).
// 32x32 swapped-operand QK^T, in-register softmax, P->A-frag via pack+shfl_xor(32).
// (r11 bug: issueK staged only half the tile; ii<4 now = full 16KB.)
__global__ __launch_bounds__(256, 2)
void attn_kernel(const short* __restrict__ C, const short* __restrict__ Vtg,
                 short* __restrict__ O) {
  __shared__ short Ks[2][8192];   // [kv 64][d 128], 16B-chunk XOR-swizzled (r&7)
  __shared__ short Vt[2][8192];   // [d 128][kv 64], 16B-chunk XOR-swizzled (d&7)
  const int tid = threadIdx.x;
  const int bid = blockIdx.x;
  const int g = bid & 7;                      // kv-head, pinned to XCD g
  const int i0 = bid >> 3;
  const int h = g * 4 + (i0 & 3);
  const int c = 15 - (i0 >> 2);               // LPT within XCD
  const int wid = tid >> 6, lane = tid & 63;
  const int q32 = lane & 31, hi = lane >> 5;
  const int qw0 = c * 128 + wid * 32;         // wave's 32 q-rows
  const int NT = 2 * c + 2;                   // 64-kv tiles

  const short* Kb = C + 4096 + g * 128;
  const short* Vb = Vtg + (size_t)g * 128 * 2048;

  s16x8 qf[8];
  f32x16 oacc[4];
  float l_part = 0.f;

  const short* Qrow = C + (size_t)(qw0 + q32) * QKV_STRIDE + h * 128 + hi * 8;
#pragma unroll
  for (int t = 0; t < 8; ++t) qf[t] = *(const s16x8*)(Qrow + t * 16);
#pragma unroll
  for (int db = 0; db < 4; ++db)
#pragma unroll
    for (int r = 0; r < 16; ++r) oacc[db][r] = 0.f;

  auto issueK = [&](int b, int kb) {
#pragma unroll
    for (int ii = 0; ii < 4; ++ii) {          // 4*256*16B = full 16KB tile
      int u = tid + ii * 256;
      int r = u >> 4, cc = u & 15;
      GLOAD_LDS16(Kb + (size_t)(kb * 64 + r) * QKV_STRIDE + ((cc ^ (r & 7)) * 8),
                  &Ks[b][u * 8]);
    }
  };
  auto issueV = [&](int b, int kb) {
#pragma unroll
    for (int ii = 0; ii < 4; ++ii) {
      int u = tid + ii * 256;
      int d = u >> 3, cc = u & 7;
      GLOAD_LDS16(Vb + (size_t)d * 2048 + kb * 64 + ((cc ^ (d & 7)) * 8),
                  &Vt[b][u * 8]);
    }
  };

  issueK(0, 0);
  issueV(0, 0);
  asm volatile("s_waitcnt vmcnt(0)" ::: "memory");
  __syncthreads();

  int buf = 0;
  for (int kb = 0; kb < NT; ++kb) {
    if (kb + 1 < NT) { issueK(buf ^ 1, kb + 1); issueV(buf ^ 1, kb + 1); }

    if (!(kb * 64 > qw0 + 31)) {               // wave not fully masked
      // ---- S^T = K Q^T : sacc[m][r] = S[k=kb*64+m*32+crow(r,hi)][q=qw0+q32] ----
      f32x16 sacc[2];
#pragma unroll
      for (int m = 0; m < 2; ++m)
#pragma unroll
        for (int r = 0; r < 16; ++r) sacc[m][r] = 0.f;
      __builtin_amdgcn_s_setprio(1);
#pragma unroll
      for (int t = 0; t < 8; ++t)
#pragma unroll
        for (int m = 0; m < 2; ++m) {
          int r = m * 32 + q32;
          s16x8 kf = *(const s16x8*)&Ks[buf][r * 128 + (((2 * t + hi) ^ (r & 7)) * 8)];
          sacc[m] = __builtin_amdgcn_mfma_f32_32x32x16_bf16(kf, qf[t], sacc[m], 0, 0, 0);
        }
      __builtin_amdgcn_s_setprio(0);

      // ---- softcap + exp (fixed max 0), causal mask ----
      const bool anymask = (kb * 64 + 63 > qw0);
#pragma unroll
      for (int m = 0; m < 2; ++m)
#pragma unroll
        for (int r = 0; r < 16; ++r) {
          float y = sacc[m][r] * SCALING_C;
          float y2 = y * y;
          float sc = y * fmaf(y2, fmaf(y2, POLY_P2, POLY_P1), 1.0f);
          float p = __expf(sc);
          if (anymask) {
            int kk = kb * 64 + m * 32 + (r & 3) + 8 * (r >> 2) + 4 * hi;
            if (kk > qw0 + q32) p = 0.f;
          }
          l_part += p;
          sacc[m][r] = p;
        }

      // ---- P -> A-frags (pack + shfl_xor 32) ; O += P V ----
#pragma unroll
      for (int ks = 0; ks < 4; ++ks) {
        const int m = ks >> 1, r0 = (ks & 1) * 8;
        unsigned a0 = pkbf(sacc[m][r0 + 0], sacc[m][r0 + 1]);
        unsigned a1 = pkbf(sacc[m][r0 + 2], sacc[m][r0 + 3]);
        unsigned b0 = pkbf(sacc[m][r0 + 4], sacc[m][r0 + 5]);
        unsigned b1 = pkbf(sacc[m][r0 + 6], sacc[m][r0 + 7]);
        unsigned xa0 = (unsigned)__shfl_xor((int)a0, 32);
        unsigned xa1 = (unsigned)__shfl_xor((int)a1, 32);
        unsigned xb0 = (unsigned)__shfl_xor((int)b0, 32);
        unsigned xb1 = (unsigned)__shfl_xor((int)b1, 32);
        union { s16x8 v; unsigned w[4]; } pw;
        pw.w[0] = hi ? xb0 : a0;
        pw.w[1] = hi ? xb1 : a1;
        pw.w[2] = hi ? b0 : xa0;
        pw.w[3] = hi ? b1 : xa1;
        __builtin_amdgcn_s_setprio(1);
#pragma unroll
        for (int db = 0; db < 4; ++db) {
          int d = db * 32 + q32;
          s16x8 vf = *(const s16x8*)&Vt[buf][d * 64 + (((2 * ks + hi) ^ (d & 7)) * 8)];
          oacc[db] = __builtin_amdgcn_mfma_f32_32x32x16_bf16(pw.v, vf, oacc[db], 0, 0, 0);
        }
        __builtin_amdgcn_s_setprio(0);
      }
    }

    // single sync point: own next-tile loads landed + everyone done reading buf
    asm volatile("s_waitcnt vmcnt(0)" ::: "memory");
    __syncthreads();
    buf ^= 1;
  }

  // ---- epilogue: l gather, divide, store ----
  float lt = l_part + __shfl_xor(l_part, 32);
  float rl[16];
#pragma unroll
  for (int r = 0; r < 16; ++r)
    rl[r] = 1.0f / __shfl(lt, (r & 3) + 8 * (r >> 2) + 4 * hi);
#pragma unroll
  for (int db = 0; db < 4; ++db)
#pragma unroll
    for (int r = 0; r < 16; ++r) {
      int q = qw0 + (r & 3) + 8 * (r >> 2) + 4 * hi;
      int d = db * 32 + q32;
      O[(size_t)q * 4096 + h * 128 + d] = f2bf(oacc[db][r] * rl[r]);
    }
}

extern "C" void kernel_launch(void* const* d_in, const int* in_sizes, int n_in,
                              void* d_out, int out_size, void* d_ws, size_t ws_size,
                              hipStream_t stream) {
  const float* hs   = (const float*)d_in[0];
  const float* cosb = (const float*)d_in[1];
  const float* sinb = (const float*)d_in[2];
  // d_in[3]: causal mask, applied analytically
  const float* Wq = (const float*)d_in[4];
  const float* Wk = (const float*)d_in[5];
  const float* Wv = (const float*)d_in[6];
  const float* Wo = (const float*)d_in[7];
  const float* qw = (const float*)d_in[8];
  const float* kw = (const float*)d_in[9];
  float* out = (float*)d_out;

  char* ws = (char*)d_ws;
  short* hsb = (short*)ws;                        // [0, 10.49M)  2048x2560
  short* WT  = (short*)(ws + 10485760);           // [10.49, 41.94M) 6144x2560 fused
  short* WkT = WT + (size_t)4096 * 2560;
  short* WvT = WT + (size_t)5120 * 2560;
  short* Cq  = (short*)(ws + 41943040);           // [41.94, 67.11M) 2048x6144 QKV
  short* ao  = (short*)ws;                        // [0, 16.78M) alias (dead after GEMMs)
  short* Vtg = (short*)(ws + 16777216);           // [16.78, 20.97M) 8x128x2048 (4MB gap)
  short* WoT = (short*)(ws + 20971520);           // [20.97, 41.94M) alias WT-tail

  dim3 blk(256), cblk(64, 4);
  convT_kernel<<<dim3(40, 64), cblk, 0, stream>>>(Wq, WT, 2560, 4096);
  convT_kernel<<<dim3(40, 16), cblk, 0, stream>>>(Wk, WkT, 2560, 1024);
  convT_kernel<<<dim3(40, 16), cblk, 0, stream>>>(Wv, WvT, 2560, 1024);
  conv16_kernel<<<5120, blk, 0, stream>>>(hs, hsb, 1310720);
  gemm_bb<1><<<dim3(48, 16), blk, 0, stream>>>(hsb, WT, Cq, 6144, 2560);
  normrope_kernel<<<16384, blk, 0, stream>>>(Cq, cosb, sinb, qw, 5, 0);
  normrope_kernel<<<4096,  blk, 0, stream>>>(Cq, cosb, sinb, kw, 3, 4096);
  transV_kernel<<<dim3(32, 2, 8), cblk, 0, stream>>>(Cq + 5120, Vtg);
  convT_kernel<<<dim3(64, 40), cblk, 0, stream>>>(Wo, WoT, 4096, 2560);
  attn_kernel<<<dim3(512), blk, 0, stream>>>(Cq, Vtg, ao);
  gemm_bb<0><<<dim3(20, 16), blk, 0, stream>>>(ao, WoT, out, 2560, 4096);
}

// Round 13
// 272.274 us; speedup vs baseline: 1.3347x; 1.0491x over previous
//
#include <hip/hip_runtime.h>
#include <hip/hip_bf16.h>

typedef __attribute__((ext_vector_type(4))) float f32x4;
typedef __attribute__((ext_vector_type(16))) float f32x16;
typedef __attribute__((ext_vector_type(4))) float fl4;
typedef __attribute__((ext_vector_type(8))) short s16x8;
typedef __attribute__((ext_vector_type(4))) short s16x4;

#define SCALING_C 0.1889822365046136f
// 50*tanh(y/50) = y*(1 + y2*(P1 + y2*P2))
#define POLY_P1 (-1.3333333333e-4f)
#define POLY_P2 (2.1333333333e-8f)
#define QKV_STRIDE 6144

__device__ __forceinline__ short f2bf(float f) {
  union { float f; unsigned u; } v; v.f = f;
  unsigned r = v.u + 0x7fffu + ((v.u >> 16) & 1u);
  return (short)(r >> 16);
}
__device__ __forceinline__ float bf2f(short s) {
  union { unsigned u; float f; } v; v.u = ((unsigned)(unsigned short)s) << 16;
  return v.f;
}
__device__ __forceinline__ unsigned pkbf(float a, float b) {
  return (unsigned)(unsigned short)f2bf(a) | ((unsigned)(unsigned short)f2bf(b) << 16);
}

#define GLOAD_LDS16(g, l)                                                          \
  __builtin_amdgcn_global_load_lds(                                                \
      (const __attribute__((address_space(1))) void*)(g),                          \
      (__attribute__((address_space(3))) void*)(l), 16, 0, 0)

// ---------------- transpose + fp32->bf16 convert: WT[n][k] = bf16(W[k][n]) -----
__global__ __launch_bounds__(256)
void convT_kernel(const float* __restrict__ W, short* __restrict__ WT, int K, int N) {
  __shared__ float T[64][65];
  const int tx = threadIdx.x, ty = threadIdx.y;   // (64,4)
  const int k0 = blockIdx.x * 64, n0 = blockIdx.y * 64;
#pragma unroll
  for (int i = 0; i < 16; ++i) {
    int r = ty + i * 4;
    T[r][tx] = W[(size_t)(k0 + r) * N + n0 + tx];
  }
  __syncthreads();
#pragma unroll
  for (int i = 0; i < 16; ++i) {
    int r = ty + i * 4;
    WT[(size_t)(n0 + r) * K + k0 + tx] = f2bf(T[tx][r]);
  }
}

// ---------------- bf16 transpose of the V slice: Vtg[g][d][kv] -----------------
__global__ __launch_bounds__(256)
void transV_kernel(const short* __restrict__ Vsrc, short* __restrict__ Vtg) {
  __shared__ short T[64][72];
  const int tx = threadIdx.x, ty = threadIdx.y;   // (64,4)
  const int kv0 = blockIdx.x * 64, d0 = blockIdx.y * 64, g = blockIdx.z;
  const short* src = Vsrc + (size_t)kv0 * QKV_STRIDE + g * 128 + d0;
#pragma unroll
  for (int i = 0; i < 16; ++i) {
    int r = ty + i * 4;
    T[r][tx] = src[(size_t)r * QKV_STRIDE + tx];
  }
  __syncthreads();
  short* dst = Vtg + (size_t)g * 128 * 2048 + (size_t)d0 * 2048 + kv0;
#pragma unroll
  for (int i = 0; i < 16; ++i) {
    int r = ty + i * 4;
    dst[(size_t)r * 2048 + tx] = T[tx][r];
  }
}

// ---------------- fp32 -> bf16 elementwise (hidden states) ----------------
__global__ __launch_bounds__(256)
void conv16_kernel(const float* __restrict__ X, short* __restrict__ Y, int n4) {
  int i = blockIdx.x * 256 + threadIdx.x;
  if (i < n4) {
    fl4 v = *(const fl4*)&X[(size_t)i * 4];
    s16x4 o;
    o[0] = f2bf(v[0]); o[1] = f2bf(v[1]); o[2] = f2bf(v[2]); o[3] = f2bf(v[3]);
    *(s16x4*)&Y[(size_t)i * 4] = o;
  }
}

// ---------------- GEMM: C = A @ Bt^T ; A MxK bf16 rows, Bt NxK bf16 rows -------
template<int OUT_BF16>
__global__ __launch_bounds__(256)
void gemm_bb(const short* __restrict__ A, const short* __restrict__ Bt,
             void* __restrict__ Cv, int N, int K) {
  __shared__ short As[8192];   // 128 rows x 64 shorts
  __shared__ short Bs[8192];
  const int tid = threadIdx.x;
  const int bm = blockIdx.y, bn = blockIdx.x;
  const int wid = tid >> 6, lane = tid & 63;
  const int wr = (wid >> 1) * 64, wc = (wid & 1) * 64;
  const int ar = lane & 15, g = lane >> 4;

  const f32x4 fz = {0.f, 0.f, 0.f, 0.f};
  f32x4 acc[4][4];
#pragma unroll
  for (int m = 0; m < 4; ++m)
#pragma unroll
    for (int n = 0; n < 4; ++n) acc[m][n] = fz;

  const short* Abase = A + (size_t)(bm * 128) * K;
  const short* Bbase = Bt + (size_t)(bn * 128) * K;
  const int u0 = wid * 256 + lane;

  for (int k0 = 0; k0 < K; k0 += 64) {
#pragma unroll
    for (int i = 0; i < 4; ++i) {
      int u = u0 + i * 64;
      int r = u >> 3;
      int cs = (u & 7) ^ (r & 7);
      size_t goff = (size_t)r * K + k0 + cs * 8;
      GLOAD_LDS16(Abase + goff, &As[(wid * 256 + i * 64) * 8]);
      GLOAD_LDS16(Bbase + goff, &Bs[(wid * 256 + i * 64) * 8]);
    }
    __syncthreads();
#pragma unroll
    for (int ks = 0; ks < 2; ++ks) {
      s16x8 af[4], bfr[4];
#pragma unroll
      for (int m = 0; m < 4; ++m) {
        int r = wr + m * 16 + ar;
        af[m] = *(const s16x8*)&As[r * 64 + (((ks * 4 + g) ^ (r & 7)) * 8)];
      }
#pragma unroll
      for (int n = 0; n < 4; ++n) {
        int r = wc + n * 16 + ar;
        bfr[n] = *(const s16x8*)&Bs[r * 64 + (((ks * 4 + g) ^ (r & 7)) * 8)];
      }
#pragma unroll
      for (int m = 0; m < 4; ++m)
#pragma unroll
        for (int n = 0; n < 4; ++n)
          acc[m][n] = __builtin_amdgcn_mfma_f32_16x16x32_bf16(af[m], bfr[n], acc[m][n], 0, 0, 0);
    }
    __syncthreads();
  }
  const int rr = (lane >> 4) * 4;
#pragma unroll
  for (int m = 0; m < 4; ++m)
#pragma unroll
    for (int n = 0; n < 4; ++n)
#pragma unroll
      for (int j = 0; j < 4; ++j) {
        int row = bm * 128 + wr + m * 16 + rr + j;
        int col = bn * 128 + wc + n * 16 + ar;
        if (OUT_BF16)
          ((short*)Cv)[(size_t)row * N + col] = f2bf(acc[m][n][j]);
        else
          ((float*)Cv)[(size_t)row * N + col] = acc[m][n][j];
      }
}

// ------- fused RMSNorm + RoPE on a column-slice of the fused QKV matrix --------
__global__ __launch_bounds__(256)
void normrope_kernel(short* __restrict__ X, const float* __restrict__ cosb,
                     const float* __restrict__ sinb, const float* __restrict__ w,
                     int hbits, int off) {
  const int wid = threadIdx.x >> 6, lane = threadIdx.x & 63;
  const int r = blockIdx.x * 4 + wid;
  const int s = r >> hbits, h = r & ((1 << hbits) - 1);
  const size_t base = (size_t)s * QKV_STRIDE + off + h * 128;
  float x1 = bf2f(X[base + lane]);
  float x2 = bf2f(X[base + 64 + lane]);
  float ss = x1 * x1 + x2 * x2;
#pragma unroll
  for (int m = 1; m < 64; m <<= 1) ss += __shfl_xor(ss, m);
  float inv = rsqrtf(ss * (1.0f / 128.0f) + 1e-6f);
  float n1 = x1 * inv * (1.0f + w[lane]);
  float n2 = x2 * inv * (1.0f + w[lane + 64]);
  float c1 = cosb[s * 128 + lane], sn1 = sinb[s * 128 + lane];
  float c2 = cosb[s * 128 + 64 + lane], sn2 = sinb[s * 128 + 64 + lane];
  X[base + lane] = f2bf(n1 * c1 - n2 * sn1);
  X[base + 64 + lane] = f2bf(n2 * c2 + n1 * sn2);
}

// ------------- flash attention v8: kv-parity split, 8 waves, XCD-pinned --------
// Block = (chunk c 128q, head h), 512 thr: waves 0-3 = even kv tiles, waves 4-7 =
// odd tiles, each parity with its own double-buffered Ks/Vt stream (128KB LDS,
// 1 block/CU). Both parities run exactly c+1 lockstep steps -> block duration
// NT/2; 512 blocks over 256 CUs = 2-round greedy LPT, near-uniform. Fixed-max
// softmax makes parity partials (O,l) exactly additive; combined once via LDS.
// All staging global_load_lds (nothing for the compiler to sink).
__global__ __launch_bounds__(512, 2)
void attn_kernel(const short* __restrict__ C, const short* __restrict__ Vtg,
                 short* __restrict__ O) {
  __shared__ short Ks[2][2][8192];   // [par][buf][kv 64][d 128], chunk-XOR (r&7)
  __shared__ short Vt[2][2][8192];   // [par][buf][d 128][kv 64], chunk-XOR (d&7)
  const int tid = threadIdx.x;
  const int par = tid >> 8;                   // kv parity
  const int t256 = tid & 255;
  const int bid = blockIdx.x;
  const int g = bid & 7;                      // kv-head, pinned to XCD g
  const int i0 = bid >> 3;
  const int h = g * 4 + (i0 & 3);
  const int c = 15 - (i0 >> 2);               // LPT: big chunks dispatch first
  const int wid4 = (tid >> 6) & 3;            // wave-in-parity: q sub-chunk
  const int lane = tid & 63;
  const int q32 = lane & 31, hi = lane >> 5;
  const int qw0 = c * 128 + wid4 * 32;        // wave's 32 q-rows
  const int NS = c + 1;                       // steps per parity (NT = 2c+2)

  const short* Kb = C + 4096 + g * 128;
  const short* Vb = Vtg + (size_t)g * 128 * 2048;

  s16x8 qf[8];
  f32x16 oacc[4];
  float l_part = 0.f;

  const short* Qrow = C + (size_t)(qw0 + q32) * QKV_STRIDE + h * 128 + hi * 8;
#pragma unroll
  for (int t = 0; t < 8; ++t) qf[t] = *(const s16x8*)(Qrow + t * 16);
#pragma unroll
  for (int db = 0; db < 4; ++db)
#pragma unroll
    for (int r = 0; r < 16; ++r) oacc[db][r] = 0.f;

  auto issueK = [&](int b, int kb) {
#pragma unroll
    for (int ii = 0; ii < 4; ++ii) {          // 4*256*16B = full 16KB tile
      int u = t256 + ii * 256;
      int r = u >> 4, cc = u & 15;
      GLOAD_LDS16(Kb + (size_t)(kb * 64 + r) * QKV_STRIDE + ((cc ^ (r & 7)) * 8),
                  &Ks[par][b][u * 8]);
    }
  };
  auto issueV = [&](int b, int kb) {
#pragma unroll
    for (int ii = 0; ii < 4; ++ii) {
      int u = t256 + ii * 256;
      int d = u >> 3, cc = u & 7;
      GLOAD_LDS16(Vb + (size_t)d * 2048 + kb * 64 + ((cc ^ (d & 7)) * 8),
                  &Vt[par][b][u * 8]);
    }
  };

  // prologue: parity's first tile is tile `par`
  issueK(0, par);
  issueV(0, par);
  asm volatile("s_waitcnt vmcnt(0)" ::: "memory");
  __syncthreads();

  int buf = 0;
  for (int step = 0; step < NS; ++step) {
    const int kb = 2 * step + par;
    if (step + 1 < NS) { issueK(buf ^ 1, kb + 2); issueV(buf ^ 1, kb + 2); }

    if (!(kb * 64 > qw0 + 31)) {               // wave not fully masked
      // ---- S^T = K Q^T : sacc[m][r] = S[k=kb*64+m*32+crow(r,hi)][q=qw0+q32] ----
      f32x16 sacc[2];
#pragma unroll
      for (int m = 0; m < 2; ++m)
#pragma unroll
        for (int r = 0; r < 16; ++r) sacc[m][r] = 0.f;
      __builtin_amdgcn_s_setprio(1);
#pragma unroll
      for (int t = 0; t < 8; ++t)
#pragma unroll
        for (int m = 0; m < 2; ++m) {
          int r = m * 32 + q32;
          s16x8 kf = *(const s16x8*)&Ks[par][buf][r * 128 + (((2 * t + hi) ^ (r & 7)) * 8)];
          sacc[m] = __builtin_amdgcn_mfma_f32_32x32x16_bf16(kf, qf[t], sacc[m], 0, 0, 0);
        }
      __builtin_amdgcn_s_setprio(0);

      // ---- softcap + exp (fixed max 0), causal mask ----
      const bool anymask = (kb * 64 + 63 > qw0);
#pragma unroll
      for (int m = 0; m < 2; ++m)
#pragma unroll
        for (int r = 0; r < 16; ++r) {
          float y = sacc[m][r] * SCALING_C;
          float y2 = y * y;
          float sc = y * fmaf(y2, fmaf(y2, POLY_P2, POLY_P1), 1.0f);
          float p = __expf(sc);
          if (anymask) {
            int kk = kb * 64 + m * 32 + (r & 3) + 8 * (r >> 2) + 4 * hi;
            if (kk > qw0 + q32) p = 0.f;
          }
          l_part += p;
          sacc[m][r] = p;
        }

      // ---- P -> A-frags (pack + shfl_xor 32) ; O += P V ----
#pragma unroll
      for (int ks = 0; ks < 4; ++ks) {
        const int m = ks >> 1, r0 = (ks & 1) * 8;
        unsigned a0 = pkbf(sacc[m][r0 + 0], sacc[m][r0 + 1]);
        unsigned a1 = pkbf(sacc[m][r0 + 2], sacc[m][r0 + 3]);
        unsigned b0 = pkbf(sacc[m][r0 + 4], sacc[m][r0 + 5]);
        unsigned b1 = pkbf(sacc[m][r0 + 6], sacc[m][r0 + 7]);
        unsigned xa0 = (unsigned)__shfl_xor((int)a0, 32);
        unsigned xa1 = (unsigned)__shfl_xor((int)a1, 32);
        unsigned xb0 = (unsigned)__shfl_xor((int)b0, 32);
        unsigned xb1 = (unsigned)__shfl_xor((int)b1, 32);
        union { s16x8 v; unsigned w[4]; } pw;
        pw.w[0] = hi ? xb0 : a0;
        pw.w[1] = hi ? xb1 : a1;
        pw.w[2] = hi ? b0 : xa0;
        pw.w[3] = hi ? b1 : xa1;
        __builtin_amdgcn_s_setprio(1);
#pragma unroll
        for (int db = 0; db < 4; ++db) {
          int d = db * 32 + q32;
          s16x8 vf = *(const s16x8*)&Vt[par][buf][d * 64 + (((2 * ks + hi) ^ (d & 7)) * 8)];
          oacc[db] = __builtin_amdgcn_mfma_f32_32x32x16_bf16(pw.v, vf, oacc[db], 0, 0, 0);
        }
        __builtin_amdgcn_s_setprio(0);
      }
    }

    // single sync point per step
    asm volatile("s_waitcnt vmcnt(0)" ::: "memory");
    __syncthreads();
    buf ^= 1;
  }

  // ---- combine parity partials (fixed-max => exactly additive) ----
  // lane-major f32 scratch: conflict-free b32 writes/reads
  float* sk = (float*)&Ks[0][0][0];            // 64KB: 256 lanes x 64 f32
  float* lv = (float*)&Vt[0][0][0];            // 1KB: 256 lanes
  const int lid = wid4 * 64 + lane;
  if (par == 1) {
#pragma unroll
    for (int db = 0; db < 4; ++db)
#pragma unroll
      for (int r = 0; r < 16; ++r) sk[lid + (db * 16 + r) * 256] = oacc[db][r];
    lv[lid] = l_part;
  }
  __syncthreads();
  if (par == 0) {
#pragma unroll
    for (int db = 0; db < 4; ++db)
#pragma unroll
      for (int r = 0; r < 16; ++r) oacc[db][r] += sk[lid + (db * 16 + r) * 256];
    l_part += lv[lid];

    // ---- epilogue: l gather, divide, store ----
    float lt = l_part + __shfl_xor(l_part, 32);
    float rl[16];
#pragma unroll
    for (int r = 0; r < 16; ++r)
      rl[r] = 1.0f / __shfl(lt, (r & 3) + 8 * (r >> 2) + 4 * hi);
#pragma unroll
    for (int db = 0; db < 4; ++db)
#pragma unroll
      for (int r = 0; r < 16; ++r) {
        int q = qw0 + (r & 3) + 8 * (r >> 2) + 4 * hi;
        int d = db * 32 + q32;
        O[(size_t)q * 4096 + h * 128 + d] = f2bf(oacc[db][r] * rl[r]);
      }
  }
}

extern "C" void kernel_launch(void* const* d_in, const int* in_sizes, int n_in,
                              void* d_out, int out_size, void* d_ws, size_t ws_size,
                              hipStream_t stream) {
  const float* hs   = (const float*)d_in[0];
  const float* cosb = (const float*)d_in[1];
  const float* sinb = (const float*)d_in[2];
  // d_in[3]: causal mask, applied analytically
  const float* Wq = (const float*)d_in[4];
  const float* Wk = (const float*)d_in[5];
  const float* Wv = (const float*)d_in[6];
  const float* Wo = (const float*)d_in[7];
  const float* qw = (const float*)d_in[8];
  const float* kw = (const float*)d_in[9];
  float* out = (float*)d_out;

  char* ws = (char*)d_ws;
  short* hsb = (short*)ws;                        // [0, 10.49M)  2048x2560
  short* WT  = (short*)(ws + 10485760);           // [10.49, 41.94M) 6144x2560 fused
  short* WkT = WT + (size_t)4096 * 2560;
  short* WvT = WT + (size_t)5120 * 2560;
  short* Cq  = (short*)(ws + 41943040);           // [41.94, 67.11M) 2048x6144 QKV
  short* ao  = (short*)ws;                        // [0, 16.78M) alias (dead after GEMMs)
  short* Vtg = (short*)(ws + 16777216);           // [16.78, 20.97M) 8x128x2048 (4MB gap)
  short* WoT = (short*)(ws + 20971520);           // [20.97, 41.94M) alias WT-tail

  dim3 blk(256), cblk(64, 4);
  convT_kernel<<<dim3(40, 64), cblk, 0, stream>>>(Wq, WT, 2560, 4096);
  convT_kernel<<<dim3(40, 16), cblk, 0, stream>>>(Wk, WkT, 2560, 1024);
  convT_kernel<<<dim3(40, 16), cblk, 0, stream>>>(Wv, WvT, 2560, 1024);
  conv16_kernel<<<5120, blk, 0, stream>>>(hs, hsb, 1310720);
  gemm_bb<1><<<dim3(48, 16), blk, 0, stream>>>(hsb, WT, Cq, 6144, 2560);
  normrope_kernel<<<16384, blk, 0, stream>>>(Cq, cosb, sinb, qw, 5, 0);
  normrope_kernel<<<4096,  blk, 0, stream>>>(Cq, cosb, sinb, kw, 3, 4096);
  transV_kernel<<<dim3(32, 2, 8), cblk, 0, stream>>>(Cq + 5120, Vtg);
  convT_kernel<<<dim3(64, 40), cblk, 0, stream>>>(Wo, WoT, 4096, 2560);
  attn_kernel<<<dim3(512), dim3(512), 0, stream>>>(Cq, Vtg, ao);
  gemm_bb<0><<<dim3(20, 16), blk, 0, stream>>>(ao, WoT, out, 2560, 4096);
}

// Round 14
// 271.964 us; speedup vs baseline: 1.3362x; 1.0011x over previous
//
#include <hip/hip_runtime.h>
#include <hip/hip_bf16.h>

typedef __attribute__((ext_vector_type(4))) float f32x4;
typedef __attribute__((ext_vector_type(16))) float f32x16;
typedef __attribute__((ext_vector_type(4))) float fl4;
typedef __attribute__((ext_vector_type(8))) short s16x8;
typedef __attribute__((ext_vector_type(4))) short s16x4;

#define SCALING_C 0.1889822365046136f
// p = exp(50*tanh(y/50)) = exp2(y*(L + y2*(P1*L + y2*P2*L))), L=log2(e)
#define L2E 1.4426950408889634f
#define PC1 (-1.9235933e-4f)   // -1/7500 * L2E
#define PC2 (3.0777493e-8f)    //  2/93750000 * L2E
#define QKV_STRIDE 6144

__device__ __forceinline__ short f2bf(float f) {
  union { float f; unsigned u; } v; v.f = f;
  unsigned r = v.u + 0x7fffu + ((v.u >> 16) & 1u);
  return (short)(r >> 16);
}
__device__ __forceinline__ float bf2f(short s) {
  union { unsigned u; float f; } v; v.u = ((unsigned)(unsigned short)s) << 16;
  return v.f;
}
__device__ __forceinline__ unsigned cvtpk(float a, float b) {
  unsigned r;
  asm("v_cvt_pk_bf16_f32 %0, %1, %2" : "=v"(r) : "v"(a), "v"(b));
  return r;   // D[15:0]=bf16(a), D[31:16]=bf16(b)
}

#define GLOAD_LDS16(g, l)                                                          \
  __builtin_amdgcn_global_load_lds(                                                \
      (const __attribute__((address_space(1))) void*)(g),                          \
      (__attribute__((address_space(3))) void*)(l), 16, 0, 0)

// ---------------- transpose + fp32->bf16 convert: WT[n][k] = bf16(W[k][n]) -----
__global__ __launch_bounds__(256)
void convT_kernel(const float* __restrict__ W, short* __restrict__ WT, int K, int N) {
  __shared__ float T[64][65];
  const int tx = threadIdx.x, ty = threadIdx.y;   // (64,4)
  const int k0 = blockIdx.x * 64, n0 = blockIdx.y * 64;
#pragma unroll
  for (int i = 0; i < 16; ++i) {
    int r = ty + i * 4;
    T[r][tx] = W[(size_t)(k0 + r) * N + n0 + tx];
  }
  __syncthreads();
#pragma unroll
  for (int i = 0; i < 16; ++i) {
    int r = ty + i * 4;
    WT[(size_t)(n0 + r) * K + k0 + tx] = f2bf(T[tx][r]);
  }
}

// ---------------- bf16 transpose of the V slice: Vtg[g][d][kv] -----------------
__global__ __launch_bounds__(256)
void transV_kernel(const short* __restrict__ Vsrc, short* __restrict__ Vtg) {
  __shared__ short T[64][72];
  const int tx = threadIdx.x, ty = threadIdx.y;   // (64,4)
  const int kv0 = blockIdx.x * 64, d0 = blockIdx.y * 64, g = blockIdx.z;
  const short* src = Vsrc + (size_t)kv0 * QKV_STRIDE + g * 128 + d0;
#pragma unroll
  for (int i = 0; i < 16; ++i) {
    int r = ty + i * 4;
    T[r][tx] = src[(size_t)r * QKV_STRIDE + tx];
  }
  __syncthreads();
  short* dst = Vtg + (size_t)g * 128 * 2048 + (size_t)d0 * 2048 + kv0;
#pragma unroll
  for (int i = 0; i < 16; ++i) {
    int r = ty + i * 4;
    dst[(size_t)r * 2048 + tx] = T[tx][r];
  }
}

// ---------------- fp32 -> bf16 elementwise (hidden states) ----------------
__global__ __launch_bounds__(256)
void conv16_kernel(const float* __restrict__ X, short* __restrict__ Y, int n4) {
  int i = blockIdx.x * 256 + threadIdx.x;
  if (i < n4) {
    fl4 v = *(const fl4*)&X[(size_t)i * 4];
    s16x4 o;
    o[0] = f2bf(v[0]); o[1] = f2bf(v[1]); o[2] = f2bf(v[2]); o[3] = f2bf(v[3]);
    *(s16x4*)&Y[(size_t)i * 4] = o;
  }
}

// ---------------- GEMM: C = A @ Bt^T ; A MxK bf16 rows, Bt NxK bf16 rows -------
template<int OUT_BF16>
__global__ __launch_bounds__(256)
void gemm_bb(const short* __restrict__ A, const short* __restrict__ Bt,
             void* __restrict__ Cv, int N, int K) {
  __shared__ short As[8192];   // 128 rows x 64 shorts
  __shared__ short Bs[8192];
  const int tid = threadIdx.x;
  const int bm = blockIdx.y, bn = blockIdx.x;
  const int wid = tid >> 6, lane = tid & 63;
  const int wr = (wid >> 1) * 64, wc = (wid & 1) * 64;
  const int ar = lane & 15, g = lane >> 4;

  const f32x4 fz = {0.f, 0.f, 0.f, 0.f};
  f32x4 acc[4][4];
#pragma unroll
  for (int m = 0; m < 4; ++m)
#pragma unroll
    for (int n = 0; n < 4; ++n) acc[m][n] = fz;

  const short* Abase = A + (size_t)(bm * 128) * K;
  const short* Bbase = Bt + (size_t)(bn * 128) * K;
  const int u0 = wid * 256 + lane;

  for (int k0 = 0; k0 < K; k0 += 64) {
#pragma unroll
    for (int i = 0; i < 4; ++i) {
      int u = u0 + i * 64;
      int r = u >> 3;
      int cs = (u & 7) ^ (r & 7);
      size_t goff = (size_t)r * K + k0 + cs * 8;
      GLOAD_LDS16(Abase + goff, &As[(wid * 256 + i * 64) * 8]);
      GLOAD_LDS16(Bbase + goff, &Bs[(wid * 256 + i * 64) * 8]);
    }
    __syncthreads();
#pragma unroll
    for (int ks = 0; ks < 2; ++ks) {
      s16x8 af[4], bfr[4];
#pragma unroll
      for (int m = 0; m < 4; ++m) {
        int r = wr + m * 16 + ar;
        af[m] = *(const s16x8*)&As[r * 64 + (((ks * 4 + g) ^ (r & 7)) * 8)];
      }
#pragma unroll
      for (int n = 0; n < 4; ++n) {
        int r = wc + n * 16 + ar;
        bfr[n] = *(const s16x8*)&Bs[r * 64 + (((ks * 4 + g) ^ (r & 7)) * 8)];
      }
#pragma unroll
      for (int m = 0; m < 4; ++m)
#pragma unroll
        for (int n = 0; n < 4; ++n)
          acc[m][n] = __builtin_amdgcn_mfma_f32_16x16x32_bf16(af[m], bfr[n], acc[m][n], 0, 0, 0);
    }
    __syncthreads();
  }
  const int rr = (lane >> 4) * 4;
#pragma unroll
  for (int m = 0; m < 4; ++m)
#pragma unroll
    for (int n = 0; n < 4; ++n)
#pragma unroll
      for (int j = 0; j < 4; ++j) {
        int row = bm * 128 + wr + m * 16 + rr + j;
        int col = bn * 128 + wc + n * 16 + ar;
        if (OUT_BF16)
          ((short*)Cv)[(size_t)row * N + col] = f2bf(acc[m][n][j]);
        else
          ((float*)Cv)[(size_t)row * N + col] = acc[m][n][j];
      }
}

// ------- fused RMSNorm + RoPE on a column-slice of the fused QKV matrix --------
// scale folds the attention SCALING into Q (1.0 for K).
__global__ __launch_bounds__(256)
void normrope_kernel(short* __restrict__ X, const float* __restrict__ cosb,
                     const float* __restrict__ sinb, const float* __restrict__ w,
                     int hbits, int off, float scale) {
  const int wid = threadIdx.x >> 6, lane = threadIdx.x & 63;
  const int r = blockIdx.x * 4 + wid;
  const int s = r >> hbits, h = r & ((1 << hbits) - 1);
  const size_t base = (size_t)s * QKV_STRIDE + off + h * 128;
  float x1 = bf2f(X[base + lane]);
  float x2 = bf2f(X[base + 64 + lane]);
  float ss = x1 * x1 + x2 * x2;
#pragma unroll
  for (int m = 1; m < 64; m <<= 1) ss += __shfl_xor(ss, m);
  float inv = rsqrtf(ss * (1.0f / 128.0f) + 1e-6f) * scale;
  float n1 = x1 * inv * (1.0f + w[lane]);
  float n2 = x2 * inv * (1.0f + w[lane + 64]);
  float c1 = cosb[s * 128 + lane], sn1 = sinb[s * 128 + lane];
  float c2 = cosb[s * 128 + 64 + lane], sn2 = sinb[s * 128 + 64 + lane];
  X[base + lane] = f2bf(n1 * c1 - n2 * sn1);
  X[base + 64 + lane] = f2bf(n2 * c2 + n1 * sn2);
}

// ------------- flash attention v9: kv-parity split + HW cvt_pk/permlane --------
// Structure as v8 (512 thr, parity dbuf streams, XCD-pinned, fixed-max softmax).
// VALU cut: Q pre-scaled (no per-element mul), softcap folded into exp2,
// v_cvt_pk_bf16_f32 packs P pairs (1 inst), v_permlane32_swap_b32 swaps halves
// (2 inst/ks, replaces 4 shfl_xor + 4 selects; mapping verified identical).
__global__ __launch_bounds__(512, 2)
void attn_kernel(const short* __restrict__ C, const short* __restrict__ Vtg,
                 short* __restrict__ O) {
  __shared__ short Ks[2][2][8192];   // [par][buf][kv 64][d 128], chunk-XOR (r&7)
  __shared__ short Vt[2][2][8192];   // [par][buf][d 128][kv 64], chunk-XOR (d&7)
  const int tid = threadIdx.x;
  const int par = tid >> 8;                   // kv parity
  const int t256 = tid & 255;
  const int bid = blockIdx.x;
  const int g = bid & 7;                      // kv-head, pinned to XCD g
  const int i0 = bid >> 3;
  const int h = g * 4 + (i0 & 3);
  const int c = 15 - (i0 >> 2);               // LPT: big chunks dispatch first
  const int wid4 = (tid >> 6) & 3;            // wave-in-parity: q sub-chunk
  const int lane = tid & 63;
  const int q32 = lane & 31, hi = lane >> 5;
  const int qw0 = c * 128 + wid4 * 32;        // wave's 32 q-rows
  const int NS = c + 1;                       // steps per parity (NT = 2c+2)

  const short* Kb = C + 4096 + g * 128;
  const short* Vb = Vtg + (size_t)g * 128 * 2048;

  s16x8 qf[8];
  f32x16 oacc[4];
  float l_part = 0.f;

  const short* Qrow = C + (size_t)(qw0 + q32) * QKV_STRIDE + h * 128 + hi * 8;
#pragma unroll
  for (int t = 0; t < 8; ++t) qf[t] = *(const s16x8*)(Qrow + t * 16);
#pragma unroll
  for (int db = 0; db < 4; ++db)
#pragma unroll
    for (int r = 0; r < 16; ++r) oacc[db][r] = 0.f;

  auto issueK = [&](int b, int kb) {
#pragma unroll
    for (int ii = 0; ii < 4; ++ii) {          // 4*256*16B = full 16KB tile
      int u = t256 + ii * 256;
      int r = u >> 4, cc = u & 15;
      GLOAD_LDS16(Kb + (size_t)(kb * 64 + r) * QKV_STRIDE + ((cc ^ (r & 7)) * 8),
                  &Ks[par][b][u * 8]);
    }
  };
  auto issueV = [&](int b, int kb) {
#pragma unroll
    for (int ii = 0; ii < 4; ++ii) {
      int u = t256 + ii * 256;
      int d = u >> 3, cc = u & 7;
      GLOAD_LDS16(Vb + (size_t)d * 2048 + kb * 64 + ((cc ^ (d & 7)) * 8),
                  &Vt[par][b][u * 8]);
    }
  };

  // prologue: parity's first tile is tile `par`
  issueK(0, par);
  issueV(0, par);
  asm volatile("s_waitcnt vmcnt(0)" ::: "memory");
  __syncthreads();

  int buf = 0;
  for (int step = 0; step < NS; ++step) {
    const int kb = 2 * step + par;
    if (step + 1 < NS) { issueK(buf ^ 1, kb + 2); issueV(buf ^ 1, kb + 2); }

    if (!(kb * 64 > qw0 + 31)) {               // wave not fully masked
      // ---- S^T = K Q^T (Q pre-scaled): sacc[m][r] = y[k=crow][q=q32] ----
      f32x16 sacc[2];
#pragma unroll
      for (int m = 0; m < 2; ++m)
#pragma unroll
        for (int r = 0; r < 16; ++r) sacc[m][r] = 0.f;
      __builtin_amdgcn_s_setprio(1);
#pragma unroll
      for (int t = 0; t < 8; ++t)
#pragma unroll
        for (int m = 0; m < 2; ++m) {
          int r = m * 32 + q32;
          s16x8 kf = *(const s16x8*)&Ks[par][buf][r * 128 + (((2 * t + hi) ^ (r & 7)) * 8)];
          sacc[m] = __builtin_amdgcn_mfma_f32_32x32x16_bf16(kf, qf[t], sacc[m], 0, 0, 0);
        }
      __builtin_amdgcn_s_setprio(0);

      // ---- softcapped exp via exp2 (fixed max 0), causal mask ----
      const bool anymask = (kb * 64 + 63 > qw0);
#pragma unroll
      for (int m = 0; m < 2; ++m)
#pragma unroll
        for (int r = 0; r < 16; ++r) {
          float y = sacc[m][r];
          float y2 = y * y;
          float z = y * fmaf(y2, fmaf(y2, PC2, PC1), L2E);
          float p = exp2f(z);
          if (anymask) {
            int kk = kb * 64 + m * 32 + (r & 3) + 8 * (r >> 2) + 4 * hi;
            if (kk > qw0 + q32) p = 0.f;
          }
          l_part += p;
          sacc[m][r] = p;
        }

      // ---- P -> A-frags: cvt_pk + permlane32_swap ; O += P V ----
#pragma unroll
      for (int ks = 0; ks < 4; ++ks) {
        const int m = ks >> 1, r0 = (ks & 1) * 8;
        unsigned a0 = cvtpk(sacc[m][r0 + 0], sacc[m][r0 + 1]);
        unsigned a1 = cvtpk(sacc[m][r0 + 2], sacc[m][r0 + 3]);
        unsigned b0 = cvtpk(sacc[m][r0 + 4], sacc[m][r0 + 5]);
        unsigned b1 = cvtpk(sacc[m][r0 + 6], sacc[m][r0 + 7]);
        // swap: a' = lane<32 ? a : b[lane-32]; b' = lane<32 ? a[lane+32] : b
        asm("v_permlane32_swap_b32 %0, %1" : "+v"(a0), "+v"(b0));
        asm("v_permlane32_swap_b32 %0, %1" : "+v"(a1), "+v"(b1));
        union { s16x8 v; unsigned w[4]; } pw;
        pw.w[0] = a0; pw.w[1] = a1; pw.w[2] = b0; pw.w[3] = b1;
        __builtin_amdgcn_s_setprio(1);
#pragma unroll
        for (int db = 0; db < 4; ++db) {
          int d = db * 32 + q32;
          s16x8 vf = *(const s16x8*)&Vt[par][buf][d * 64 + (((2 * ks + hi) ^ (d & 7)) * 8)];
          oacc[db] = __builtin_amdgcn_mfma_f32_32x32x16_bf16(pw.v, vf, oacc[db], 0, 0, 0);
        }
        __builtin_amdgcn_s_setprio(0);
      }
    }

    // single sync point per step
    asm volatile("s_waitcnt vmcnt(0)" ::: "memory");
    __syncthreads();
    buf ^= 1;
  }

  // ---- combine parity partials (fixed-max => exactly additive) ----
  float* sk = (float*)&Ks[0][0][0];            // 64KB: 256 lanes x 64 f32
  float* lv = (float*)&Vt[0][0][0];            // 1KB: 256 lanes
  const int lid = wid4 * 64 + lane;
  if (par == 1) {
#pragma unroll
    for (int db = 0; db < 4; ++db)
#pragma unroll
      for (int r = 0; r < 16; ++r) sk[lid + (db * 16 + r) * 256] = oacc[db][r];
    lv[lid] = l_part;
  }
  __syncthreads();
  if (par == 0) {
#pragma unroll
    for (int db = 0; db < 4; ++db)
#pragma unroll
      for (int r = 0; r < 16; ++r) oacc[db][r] += sk[lid + (db * 16 + r) * 256];
    l_part += lv[lid];

    // ---- epilogue: l gather, divide, store ----
    float lt = l_part + __shfl_xor(l_part, 32);
    float rl[16];
#pragma unroll
    for (int r = 0; r < 16; ++r)
      rl[r] = 1.0f / __shfl(lt, (r & 3) + 8 * (r >> 2) + 4 * hi);
#pragma unroll
    for (int db = 0; db < 4; ++db)
#pragma unroll
      for (int r = 0; r < 16; ++r) {
        int q = qw0 + (r & 3) + 8 * (r >> 2) + 4 * hi;
        int d = db * 32 + q32;
        O[(size_t)q * 4096 + h * 128 + d] = f2bf(oacc[db][r] * rl[r]);
      }
  }
}

extern "C" void kernel_launch(void* const* d_in, const int* in_sizes, int n_in,
                              void* d_out, int out_size, void* d_ws, size_t ws_size,
                              hipStream_t stream) {
  const float* hs   = (const float*)d_in[0];
  const float* cosb = (const float*)d_in[1];
  const float* sinb = (const float*)d_in[2];
  // d_in[3]: causal mask, applied analytically
  const float* Wq = (const float*)d_in[4];
  const float* Wk = (const float*)d_in[5];
  const float* Wv = (const float*)d_in[6];
  const float* Wo = (const float*)d_in[7];
  const float* qw = (const float*)d_in[8];
  const float* kw = (const float*)d_in[9];
  float* out = (float*)d_out;

  char* ws = (char*)d_ws;
  short* hsb = (short*)ws;                        // [0, 10.49M)  2048x2560
  short* WT  = (short*)(ws + 10485760);           // [10.49, 41.94M) 6144x2560 fused
  short* WkT = WT + (size_t)4096 * 2560;
  short* WvT = WT + (size_t)5120 * 2560;
  short* Cq  = (short*)(ws + 41943040);           // [41.94, 67.11M) 2048x6144 QKV
  short* ao  = (short*)ws;                        // [0, 16.78M) alias (dead after GEMMs)
  short* Vtg = (short*)(ws + 16777216);           // [16.78, 20.97M) 8x128x2048 (4MB gap)
  short* WoT = (short*)(ws + 20971520);           // [20.97, 41.94M) alias WT-tail

  dim3 blk(256), cblk(64, 4);
  convT_kernel<<<dim3(40, 64), cblk, 0, stream>>>(Wq, WT, 2560, 4096);
  convT_kernel<<<dim3(40, 16), cblk, 0, stream>>>(Wk, WkT, 2560, 1024);
  convT_kernel<<<dim3(40, 16), cblk, 0, stream>>>(Wv, WvT, 2560, 1024);
  conv16_kernel<<<5120, blk, 0, stream>>>(hs, hsb, 1310720);
  gemm_bb<1><<<dim3(48, 16), blk, 0, stream>>>(hsb, WT, Cq, 6144, 2560);
  normrope_kernel<<<16384, blk, 0, stream>>>(Cq, cosb, sinb, qw, 5, 0, SCALING_C);
  normrope_kernel<<<4096,  blk, 0, stream>>>(Cq, cosb, sinb, kw, 3, 4096, 1.0f);
  transV_kernel<<<dim3(32, 2, 8), cblk, 0, stream>>>(Cq + 5120, Vtg);
  convT_kernel<<<dim3(64, 40), cblk, 0, stream>>>(Wo, WoT, 4096, 2560);
  attn_kernel<<<dim3(512), dim3(512), 0, stream>>>(Cq, Vtg, ao);
  gemm_bb<0><<<dim3(20, 16), blk, 0, stream>>>(ao, WoT, out, 2560, 4096);
}